// Round 10
// baseline (388.727 us; speedup 1.0000x reference)
//
#include <hip/hip_runtime.h>
#include <hip/hip_bf16.h>
#include <stdint.h>

typedef __attribute__((ext_vector_type(8))) short short8;
typedef __attribute__((ext_vector_type(16))) float floatx16;
typedef unsigned short u16;

#define IN_DIM  1024
#define OUT_DIM 1024
#define NG      11            // spline bases per channel
#define GK      12            // + silu slot
#define KDIM    (IN_DIM * GK) // 12288
#define TOKENS  8192

// ---- main GEMM params (v10: BK=32, triple-buffered, prefetch distance 3)
#define QBK   32              // K elems per tile (2 k-steps of 16)
#define QROW  40              // LDS row stride elems: 5 granules (4 data + 1 pad-dup)
                              // stride 80B = 20 dw == 20 mod 32 -> same verified rotation
                              // class as PB=104 (52 dw == 20) / GR=9 (36 dw == 4): 0 conflicts.
#define QSLOT (256 * QROW)    // 10240 u16 = 20480 B per operand-slot
#define QOPS  5               // vmem ops per wave per tile (40 total: 20 A + 20 B)

// ---- fallback fused-path params (round-5 kernel, verified pass)
#define FBK     48
#define FROW    56
#define FBUF    (256 * FROW)
#define FOPS    4

__device__ __forceinline__ u16 f2bf(float f) {
  uint32_t u = __float_as_uint(f);
  uint32_t r = (u + 0x7fffu + ((u >> 16) & 1u)) >> 16;  // RNE
  return (u16)r;
}

// Closed-form cubic B-spline + silu -> 3 u64 (verified, absmax 0.125)
__device__ __forceinline__ void expand_regs(float x, float g0, float inv_h,
                                            uint64_t& V0, uint64_t& V1, uint64_t& V2)
{
  float t  = (x - g0) * inv_h;
  float fc = floorf(t);
  int   c  = (int)fc;
  float u  = t - fc;
  float u2 = u * u;
  float w1 = 1.0f - u;
  float b0 = (w1 * w1 * w1) * (1.0f / 6.0f);
  float b1 = (0.5f * u - 1.0f) * u2 + (2.0f / 3.0f);
  float b2 = ((-0.5f * u + 0.5f) * u + 0.5f) * u + (1.0f / 6.0f);
  float b3 = (u2 * u) * (1.0f / 6.0f);
  float sil = x / (1.0f + __expf(-x));

  uint64_t P = (uint64_t)f2bf(b0) | ((uint64_t)f2bf(b1) << 16)
             | ((uint64_t)f2bf(b2) << 32) | ((uint64_t)f2bf(b3) << 48);
  int  k  = c - 3;
  bool cv = (c >= 0) && (c <= 13);
  int  kneg = (k < 0) ? -k : 0;
  uint64_t Pc = cv ? (P >> (16 * kneg)) : 0ull;
  uint32_t sh = (uint32_t)(16 * ((k < 0) ? 0 : k));

  V0 = (sh < 64)  ? (Pc << (sh & 63)) : 0ull;
  V1 = (sh == 0)  ? 0ull :
       (sh < 64)  ? (Pc >> ((64 - sh) & 63)) :
       (sh < 128) ? (Pc << ((sh - 64) & 63)) : 0ull;
  V2 = (sh <= 64) ? 0ull :
       (sh < 128) ? (Pc >> ((128 - sh) & 63)) :
                    (Pc << ((sh - 128) & 63));
  V2 = (V2 & 0x0000FFFFFFFFFFFFull) | ((uint64_t)f2bf(sil) << 48);
}

__device__ __forceinline__ void async16(const u16* g, u16* l) {
  __builtin_amdgcn_global_load_lds(
      (const __attribute__((address_space(1))) uint32_t*)g,
      (__attribute__((address_space(3))) uint32_t*)l,
      16, 0, 0);
}

// ---------------- prep: pack Wt (blocks 0..4095) + expand X (blocks 4096..6143).
__global__ __launch_bounds__(256) void prep_kernel(
    const float* __restrict__ coeff, const float* __restrict__ sb,
    const float* __restrict__ ss_p, u16* __restrict__ Wt,
    const float* __restrict__ X, const float* __restrict__ grid,
    u16* __restrict__ Aexp)
{
  __shared__ __align__(16) char smem_c[24576];
  const int tid = threadIdx.x;

  if (blockIdx.x < 4096) {
    // ---- pack Wt: bf16 [OUT_DIM][KDIM] (verified)
    float* cf = (float*)smem_c;                 // 11264 B
    u16*   st = (u16*)(smem_c + 11264);         // 6144 B
    const int b   = blockIdx.x;
    const int o   = b >> 2;
    const int i0  = (b & 3) * 256;
    const float* cbase = coeff + (size_t)o * (IN_DIM * NG) + (size_t)i0 * NG;
#pragma unroll
    for (int p = 0; p < NG; ++p) cf[p * 256 + tid] = cbase[p * 256 + tid];
    const float ss  = ss_p[0];
    const float sbv = sb[(size_t)o * IN_DIM + i0 + tid];
    __syncthreads();
    const float* cp = cf + tid * NG;
    u16 h[GK];
#pragma unroll
    for (int g = 0; g < NG; ++g) h[g] = f2bf(cp[g] * ss);
    h[NG] = f2bf(sbv);
    uint64_t V0 = (uint64_t)h[0] | ((uint64_t)h[1] << 16) | ((uint64_t)h[2] << 32) | ((uint64_t)h[3] << 48);
    uint64_t V1 = (uint64_t)h[4] | ((uint64_t)h[5] << 16) | ((uint64_t)h[6] << 32) | ((uint64_t)h[7] << 48);
    uint64_t V2 = (uint64_t)h[8] | ((uint64_t)h[9] << 16) | ((uint64_t)h[10] << 32) | ((uint64_t)h[11] << 48);
    uint64_t* sp = (uint64_t*)(st + tid * GK);
    sp[0] = V0; sp[1] = V1; sp[2] = V2;
    __syncthreads();
    const uint4* src = (const uint4*)st;
    uint4* dst = (uint4*)(Wt + (size_t)b * (256 * GK));
    dst[tid] = src[tid];
    if (tid < 128) dst[256 + tid] = src[256 + tid];
  } else {
    // ---- expand X -> Aexp[TOKENS][KDIM] bf16, 4 rows/block, LDS funnel
    uint4* st4 = (uint4*)smem_c;                // 24576 B = one expanded row
    const float g0    = grid[0];
    const float inv_h = 1.0f / (grid[1] - grid[0]);
    const int bb = blockIdx.x - 4096;
    for (int rr = 0; rr < 4; ++rr) {
      const int row = bb * 4 + rr;
      float4 xv = *(const float4*)(X + (size_t)row * IN_DIM + tid * 4);
      uint64_t ev[12];
      expand_regs(xv.x, g0, inv_h, ev[0], ev[1], ev[2]);
      expand_regs(xv.y, g0, inv_h, ev[3], ev[4], ev[5]);
      expand_regs(xv.z, g0, inv_h, ev[6], ev[7], ev[8]);
      expand_regs(xv.w, g0, inv_h, ev[9], ev[10], ev[11]);
      if (rr) __syncthreads();
#pragma unroll
      for (int j = 0; j < 6; ++j) {
        uint4 w;
        w.x = (uint32_t)ev[2*j];     w.y = (uint32_t)(ev[2*j] >> 32);
        w.z = (uint32_t)ev[2*j+1];   w.w = (uint32_t)(ev[2*j+1] >> 32);
        st4[tid * 6 + j] = w;
      }
      __syncthreads();
      uint4* dst = (uint4*)(Aexp + (size_t)row * KDIM);
#pragma unroll
      for (int j = 0; j < 6; ++j) dst[j * 256 + tid] = st4[j * 256 + tid];
    }
  }
}

// ---------------- GEMM v10: 256x256 tile, BK=32, TRIPLE-buffered slots,
// prefetch distance 3 tiles, counted vmcnt(10).
// r9 POST-MORTEM: XCD-resident-B didn't help (230 vs 216) -> NOT LLC-BW-bound.
// All pipes <45% busy in r4 -> latency/sync-bound: 1-tile prefetch distance
// (~2065 cyc) barely covers barrier-aligned burst latency. Fix (m201's T4):
// deepen the pipeline. At boundary(t), slot t%3 was just freed (its tile
// read during compute(t)); stage tile t+3 into it -> ~3 tiles (~3100 cyc)
// coverage. 40 ops/tile = exactly 5/wave; vmcnt counts in ISSUE order
// (m135), so after issuing t+3's 5 ops, vmcnt(10) certifies tile t+1
// (completed >= issued-10 = 5(t+2) ops). Tail: vmcnt(5) / vmcnt(0).
// Pad-granule rows (5 granules, stride 80B == 20 dw mod 32 = verified-0-
// conflict class). Block map / epilogue / reduce identical to r4 (best).
__global__ __launch_bounds__(512, 2) void gemm_pre_kernel(
    const u16* __restrict__ A, const u16* __restrict__ Wt,
    float* __restrict__ out, float* __restrict__ part, int k_iters)
{
  __shared__ __align__(16) u16 S[6 * QSLOT];   // A:slots 0-2, B:slots 3-5 = 122880 B

  const int tid  = threadIdx.x;
  const int lane = tid & 63;
  const int wave = tid >> 6;              // 0..7
  const int s    = blockIdx.x >> 7;       // 2 K-splits
  const int r    = blockIdx.x & 127;
  const int bm   = r & 31;                // bid%8 = bm%8 -> A-strip sharers on one XCD
  const int bn   = r >> 5;
  const int wm   = (wave >> 2) * 128;     // 2 M-warps
  const int wn   = (wave & 3) * 64;       // 4 N-warps
  const int l31  = lane & 31;
  const int g8   = lane >> 5;

  floatx16 acc[4][2];
#pragma unroll
  for (int a = 0; a < 4; ++a)
#pragma unroll
    for (int b = 0; b < 2; ++b)
#pragma unroll
      for (int rr = 0; rr < 16; ++rr) acc[a][b][rr] = 0.f;

  // DMA setup: combined op q = wave + 8j (j<5, q<40): q<20 -> A op q, else
  // B op q-20. lane: gidx = oq*64+lane (<1280); row = gidx/5; chunk = gidx%5;
  // chunk 4 = pad -> harmless dup of chunk 0. dof includes the A/B base;
  // slot p adds p*QSLOT (same offset for both operands).
  const size_t k0 = (size_t)s * k_iters * QBK;
  const u16* src[QOPS]; int dof[QOPS];
#pragma unroll
  for (int j = 0; j < QOPS; ++j) {
    int q    = wave + 8 * j;
    bool isA = (q < 20);
    int oq   = isA ? q : q - 20;
    int gidx  = oq * 64 + lane;
    int row   = gidx / 5;
    int chunk = gidx - row * 5;
    int c4    = (chunk == 4) ? 0 : chunk;
    src[j] = (isA ? A + (size_t)(bm * 256 + row) * KDIM
                  : Wt + (size_t)(bn * 256 + row) * KDIM) + k0 + c4 * 8;
    dof[j] = (isA ? 0 : 3 * QSLOT) + oq * 512;   // 64 granules = 1024 B per op
  }

  const int NT = k_iters;   // >= 3

  // prologue: stage tiles 0,1,2 into slots 0,1,2; vmcnt(10) -> tile 0 done.
#pragma unroll
  for (int j = 0; j < QOPS; ++j) async16(src[j],           S + 0 * QSLOT + dof[j]);
#pragma unroll
  for (int j = 0; j < QOPS; ++j) async16(src[j] + QBK,     S + 1 * QSLOT + dof[j]);
#pragma unroll
  for (int j = 0; j < QOPS; ++j) async16(src[j] + 2 * QBK, S + 2 * QSLOT + dof[j]);
  asm volatile("s_waitcnt vmcnt(10)" ::: "memory");
  __builtin_amdgcn_s_barrier();
  __builtin_amdgcn_sched_barrier(0);

  int p = 0;  // slot index = t % 3
  for (int t = 0; t < NT; ++t) {
    const u16* Ab = S + p * QSLOT;
    const u16* Bb = S + 3 * QSLOT + p * QSLOT;

    __builtin_amdgcn_s_setprio(1);
#pragma unroll
    for (int ks = 0; ks < 2; ++ks) {
      short8 bf0 = *(const short8*)&Bb[(wn +      l31) * QROW + (2 * ks + g8) * 8];
      short8 bf1 = *(const short8*)&Bb[(wn + 32 + l31) * QROW + (2 * ks + g8) * 8];
#pragma unroll
      for (int m = 0; m < 4; ++m) {
        short8 af = *(const short8*)&Ab[(wm + m * 32 + l31) * QROW + (2 * ks + g8) * 8];
        acc[m][0] = __builtin_amdgcn_mfma_f32_32x32x16_bf16(af, bf0, acc[m][0], 0, 0, 0);
        acc[m][1] = __builtin_amdgcn_mfma_f32_32x32x16_bf16(af, bf1, acc[m][1], 0, 0, 0);
      }
    }
    __builtin_amdgcn_s_setprio(0);

    __builtin_amdgcn_s_barrier();          // all waves done reading slot p
    __builtin_amdgcn_sched_barrier(0);
    if (t + 3 < NT) {
      u16* D = S + p * QSLOT;              // slot p just freed; (t+3)%3 == p
      const size_t ko = (size_t)(t + 3) * QBK;
#pragma unroll
      for (int j = 0; j < QOPS; ++j) async16(src[j] + ko, D + dof[j]);
      asm volatile("s_waitcnt vmcnt(10)" ::: "memory");  // certifies tile t+1
    } else if (t + 2 < NT) {
      asm volatile("s_waitcnt vmcnt(5)" ::: "memory");   // t+2 may stay in flight
    } else if (t + 1 < NT) {
      asm volatile("s_waitcnt vmcnt(0)" ::: "memory");
    }
    __builtin_amdgcn_s_barrier();          // slot (t+1)%3 ready
    __builtin_amdgcn_sched_barrier(0);

    p = (p == 2) ? 0 : p + 1;
  }

  // C/D map (m74/m101-verified): col=lane&31, row=(reg&3)+8*(reg>>2)+4*(lane>>5)
  float* op = (s == 0) ? out : part;
#pragma unroll
  for (int m = 0; m < 4; ++m)
#pragma unroll
    for (int n = 0; n < 2; ++n) {
      const int row0 = bm * 256 + wm + m * 32 + 4 * g8;
      const int col  = bn * 256 + wn + n * 32 + l31;
#pragma unroll
      for (int reg = 0; reg < 16; ++reg) {
        int row = row0 + (reg & 3) + 8 * (reg >> 2);
        op[(size_t)row * OUT_DIM + col] = acc[m][n][reg];
      }
    }
}

// out += part, float4-vectorized
__global__ __launch_bounds__(256) void reduce_kernel(
    float* __restrict__ out, const float* __restrict__ part)
{
  size_t i = (size_t)blockIdx.x * 256 + threadIdx.x;
  float4* o = (float4*)out;
  const float4* p = (const float4*)part;
  float4 a = o[i], b = p[i];
  a.x += b.x; a.y += b.y; a.z += b.z; a.w += b.w;
  o[i] = a;
}

// ---------------- fallback path (round-5 fused kernel, verified pass) ----------------
__device__ __forceinline__ void expand2(float2 xv, float g0, float inv_h, uint64_t e[6]) {
  expand_regs(xv.x, g0, inv_h, e[0], e[1], e[2]);
  expand_regs(xv.y, g0, inv_h, e[3], e[4], e[5]);
}
__device__ __forceinline__ void write_ev(u16* abase, int awoff, const uint64_t e[6]) {
  uint4* w = (uint4*)(abase + awoff);
  uint4 w0, w1, w2;
  w0.x = (uint32_t)e[0]; w0.y = (uint32_t)(e[0] >> 32);
  w0.z = (uint32_t)e[1]; w0.w = (uint32_t)(e[1] >> 32);
  w1.x = (uint32_t)e[2]; w1.y = (uint32_t)(e[2] >> 32);
  w1.z = (uint32_t)e[3]; w1.w = (uint32_t)(e[3] >> 32);
  w2.x = (uint32_t)e[4]; w2.y = (uint32_t)(e[4] >> 32);
  w2.z = (uint32_t)e[5]; w2.w = (uint32_t)(e[5] >> 32);
  w[0] = w0; w[1] = w1; w[2] = w2;
}

__global__ __launch_bounds__(256) void pack_wt_kernel(
    const float* __restrict__ coeff, const float* __restrict__ sb,
    const float* __restrict__ ss_p, u16* __restrict__ Wt)
{
  __shared__ float cf[256 * NG];
  __shared__ __align__(16) u16 st[256 * GK];
  const int tid = threadIdx.x;
  const int b   = blockIdx.x;
  const int o   = b >> 2;
  const int i0  = (b & 3) * 256;
  const float* cbase = coeff + (size_t)o * (IN_DIM * NG) + (size_t)i0 * NG;
#pragma unroll
  for (int p = 0; p < NG; ++p) cf[p * 256 + tid] = cbase[p * 256 + tid];
  const float ss  = ss_p[0];
  const float sbv = sb[(size_t)o * IN_DIM + i0 + tid];
  __syncthreads();
  const float* cp = cf + tid * NG;
  u16 h[GK];
#pragma unroll
  for (int g = 0; g < NG; ++g) h[g] = f2bf(cp[g] * ss);
  h[NG] = f2bf(sbv);
  uint64_t V0 = (uint64_t)h[0] | ((uint64_t)h[1] << 16) | ((uint64_t)h[2] << 32) | ((uint64_t)h[3] << 48);
  uint64_t V1 = (uint64_t)h[4] | ((uint64_t)h[5] << 16) | ((uint64_t)h[6] << 32) | ((uint64_t)h[7] << 48);
  uint64_t V2 = (uint64_t)h[8] | ((uint64_t)h[9] << 16) | ((uint64_t)h[10] << 32) | ((uint64_t)h[11] << 48);
  uint64_t* sp = (uint64_t*)(st + tid * GK);
  sp[0] = V0; sp[1] = V1; sp[2] = V2;
  __syncthreads();
  const uint4* src = (const uint4*)st;
  uint4* dst = (uint4*)(Wt + (size_t)b * (256 * GK));
  dst[tid] = src[tid];
  if (tid < 128) dst[256 + tid] = src[256 + tid];
}

__global__ __launch_bounds__(512, 2) void gemm_fused2_kernel(
    const float* __restrict__ X, const float* __restrict__ grid,
    const u16* __restrict__ Wt, float* __restrict__ out, float* __restrict__ part,
    int k_iters)
{
  __shared__ __align__(16) u16 S[4 * FBUF];

  const int tid  = threadIdx.x;
  const int lane = tid & 63;
  const int wave = tid >> 6;
  const int s    = blockIdx.x >> 7;
  const int r    = blockIdx.x & 127;
  const int bm   = r & 31;
  const int bn   = r >> 5;
  const int wm   = (wave >> 2) * 128;
  const int wn   = (wave & 3) * 64;
  const int l31  = lane & 31;
  const int g8   = lane >> 5;

  const float g0    = grid[0];
  const float inv_h = 1.0f / (grid[1] - grid[0]);

  floatx16 acc[4][2];
#pragma unroll
  for (int a = 0; a < 4; ++a)
#pragma unroll
    for (int b = 0; b < 2; ++b)
#pragma unroll
      for (int rr = 0; rr < 16; ++rr) acc[a][b][rr] = 0.f;

  const int kb = s * k_iters * FBK;
  const u16* bsrc[FOPS]; int bdof[FOPS];
#pragma unroll
  for (int j = 0; j < FOPS; ++j) {
    int o  = wave + 8 * j;
    int oc = (o < 28) ? o : 27;
    int gidx = oc * 64 + lane;
    int row  = gidx / 7;
    int sl   = gidx - row * 7;
    int c6   = (sl == 6) ? 0 : sl;
    bsrc[j] = Wt + (size_t)(bn * 256 + row) * KDIM + kb + c6 * 8;
    bdof[j] = oc * 512;
  }

  const int arow  = tid >> 1;
  const int cp    = (tid & 1) * 2;
  const float* xp = X + (size_t)(bm * 256 + arow) * IN_DIM + s * (k_iters * 4) + cp;
  const int awoff = arow * FROW + cp * 12;

  const int NT = k_iters;

  float2 x0    = *(const float2*)(xp + 0);
  float2 x1    = *(const float2*)(xp + 4);
  float2 x_use = *(const float2*)(xp + 8);
  float2 x_mid = *(const float2*)(xp + 12);
  float2 x_new = x_use;

#pragma unroll
  for (int j = 0; j < FOPS; ++j) async16(bsrc[j],       S + 2 * FBUF + bdof[j]);
#pragma unroll
  for (int j = 0; j < FOPS; ++j) async16(bsrc[j] + FBK, S + 3 * FBUF + bdof[j]);
  {
    uint64_t e[6];
    expand2(x0, g0, inv_h, e); write_ev(S, awoff, e);
    expand2(x1, g0, inv_h, e); write_ev(S + FBUF, awoff, e);
  }
  asm volatile("s_waitcnt vmcnt(0) lgkmcnt(0)" ::: "memory");
  __builtin_amdgcn_s_barrier();
  __builtin_amdgcn_sched_barrier(0);

  for (int t = 0; t < NT; ++t) {
    const int p = t & 1;
    const u16* Ab = S + p * FBUF;
    const u16* Bb = S + 2 * FBUF + p * FBUF;

    uint64_t e[6];
    const bool dostage = (t + 2 < NT);
    if (dostage) expand2(x_use, g0, inv_h, e);

    __builtin_amdgcn_s_setprio(1);
#pragma unroll
    for (int ks = 0; ks < 3; ++ks) {
      const int cc = (2 * ks + g8) * 8;
      short8 bf0 = *(const short8*)&Bb[(wn +      l31) * FROW + cc];
      short8 bf1 = *(const short8*)&Bb[(wn + 32 + l31) * FROW + cc];
#pragma unroll
      for (int m = 0; m < 4; ++m) {
        short8 af = *(const short8*)&Ab[(wm + m * 32 + l31) * FROW + cc];
        acc[m][0] = __builtin_amdgcn_mfma_f32_32x32x16_bf16(af, bf0, acc[m][0], 0, 0, 0);
        acc[m][1] = __builtin_amdgcn_mfma_f32_32x32x16_bf16(af, bf1, acc[m][1], 0, 0, 0);
      }
    }
    __builtin_amdgcn_s_setprio(0);

    __builtin_amdgcn_s_barrier();
    __builtin_amdgcn_sched_barrier(0);

    if (dostage) {
      const int ko = (t + 2) * FBK;
      u16* Bd = S + 2 * FBUF + p * FBUF;
#pragma unroll
      for (int j = 0; j < FOPS; ++j) async16(bsrc[j] + ko, Bd + bdof[j]);
      write_ev(S + p * FBUF, awoff, e);
      if (t + 4 < NT) {
        x_new = *(const float2*)(xp + (size_t)(t + 4) * 4);
        asm volatile("s_waitcnt vmcnt(5) lgkmcnt(0)" ::: "memory");
      } else {
        asm volatile("s_waitcnt vmcnt(4) lgkmcnt(0)" ::: "memory");
      }
    } else {
      asm volatile("s_waitcnt vmcnt(0) lgkmcnt(0)" ::: "memory");
    }
    __builtin_amdgcn_s_barrier();
    __builtin_amdgcn_sched_barrier(0);

    x_use = x_mid; x_mid = x_new;
  }

  float* op = (s == 0) ? out : part;
#pragma unroll
  for (int m = 0; m < 4; ++m)
#pragma unroll
    for (int n = 0; n < 2; ++n) {
      const int row0 = bm * 256 + wm + m * 32 + 4 * g8;
      const int col  = bn * 256 + wn + n * 32 + l31;
#pragma unroll
      for (int reg = 0; reg < 16; ++reg) {
        int row = row0 + (reg & 3) + 8 * (reg >> 2);
        op[(size_t)row * OUT_DIM + col] = acc[m][n][reg];
      }
    }
}

extern "C" void kernel_launch(void* const* d_in, const int* in_sizes, int n_in,
                              void* d_out, int out_size, void* d_ws, size_t ws_size,
                              hipStream_t stream) {
  const float* x     = (const float*)d_in[0];
  const float* grid  = (const float*)d_in[1];
  const float* coeff = (const float*)d_in[2];
  const float* sb    = (const float*)d_in[3];
  const float* ss    = (const float*)d_in[4];
  float* out = (float*)d_out;

  u16* Wt = (u16*)d_ws;
  const size_t wt_bytes   = (size_t)OUT_DIM * KDIM * 2;     // 25.2 MB
  const size_t aexp_bytes = (size_t)TOKENS * KDIM * 2;      // 201.3 MB
  const size_t part_bytes = (size_t)TOKENS * OUT_DIM * 4;   // 33.6 MB

  if (ws_size >= wt_bytes + aexp_bytes + part_bytes) {
    // main path: fused prep, triple-buffered GEMM (split-K=2, 192 tiles of 32), reduce.
    u16*   Aexp = (u16*)((char*)d_ws + wt_bytes);
    float* part = (float*)((char*)d_ws + wt_bytes + aexp_bytes);
    prep_kernel<<<4096 + TOKENS / 4, 256, 0, stream>>>(coeff, sb, ss, Wt, x, grid, Aexp);
    gemm_pre_kernel<<<128 * 2, 512, 0, stream>>>(Aexp, Wt, out, part, 192);
    reduce_kernel<<<(TOKENS * OUT_DIM / 4) / 256, 256, 0, stream>>>(out, part);
  } else if (ws_size >= wt_bytes + part_bytes) {
    // fallback: fused split-K=2 (round-5 kernel, verified)
    float* part = (float*)((char*)d_ws + wt_bytes);
    pack_wt_kernel<<<(OUT_DIM * IN_DIM) / 256, 256, 0, stream>>>(coeff, sb, ss, Wt);
    gemm_fused2_kernel<<<128 * 2, 512, 0, stream>>>(x, grid, Wt, out, part, 128);
    reduce_kernel<<<(TOKENS * OUT_DIM / 4) / 256, 256, 0, stream>>>(out, part);
  } else {
    pack_wt_kernel<<<(OUT_DIM * IN_DIM) / 256, 256, 0, stream>>>(coeff, sb, ss, Wt);
    gemm_fused2_kernel<<<128, 512, 0, stream>>>(x, grid, Wt, out, nullptr, 256);
  }
}

// Round 11
// 368.050 us; speedup vs baseline: 1.0562x; 1.0562x over previous
//
#include <hip/hip_runtime.h>
#include <hip/hip_bf16.h>
#include <stdint.h>

typedef __attribute__((ext_vector_type(8))) short short8;
typedef __attribute__((ext_vector_type(16))) float floatx16;
typedef unsigned short u16;

#define IN_DIM  1024
#define OUT_DIM 1024
#define NG      11            // spline bases per channel
#define GK      12            // + silu slot
#define KDIM    (IN_DIM * GK) // 12288
#define TOKENS  8192

// ---- main GEMM params (round-4 verified core: best measured, 216us/41%)
#define GBK     64            // K elems per tile (4 k-steps of 16)
#define G2R     9             // LDS granules/row: 8 data + 1 pad (odd -> bank rotation)
#define G2OPS   36            // 256 rows * 9 granules / 64 lanes (per operand)
#define ABUF    (256 * 72)    // u16 elems per operand-parity buffer (36864 B)

// ---- fallback fused-path params (round-5 kernel, verified pass)
#define FBK     48
#define FROW    56
#define FBUF    (256 * FROW)
#define FOPS    4

__device__ __forceinline__ u16 f2bf(float f) {
  uint32_t u = __float_as_uint(f);
  uint32_t r = (u + 0x7fffu + ((u >> 16) & 1u)) >> 16;  // RNE
  return (u16)r;
}

// Closed-form cubic B-spline + silu -> 3 u64 (verified, absmax 0.125)
__device__ __forceinline__ void expand_regs(float x, float g0, float inv_h,
                                            uint64_t& V0, uint64_t& V1, uint64_t& V2)
{
  float t  = (x - g0) * inv_h;
  float fc = floorf(t);
  int   c  = (int)fc;
  float u  = t - fc;
  float u2 = u * u;
  float w1 = 1.0f - u;
  float b0 = (w1 * w1 * w1) * (1.0f / 6.0f);
  float b1 = (0.5f * u - 1.0f) * u2 + (2.0f / 3.0f);
  float b2 = ((-0.5f * u + 0.5f) * u + 0.5f) * u + (1.0f / 6.0f);
  float b3 = (u2 * u) * (1.0f / 6.0f);
  float sil = x / (1.0f + __expf(-x));

  uint64_t P = (uint64_t)f2bf(b0) | ((uint64_t)f2bf(b1) << 16)
             | ((uint64_t)f2bf(b2) << 32) | ((uint64_t)f2bf(b3) << 48);
  int  k  = c - 3;
  bool cv = (c >= 0) && (c <= 13);
  int  kneg = (k < 0) ? -k : 0;
  uint64_t Pc = cv ? (P >> (16 * kneg)) : 0ull;
  uint32_t sh = (uint32_t)(16 * ((k < 0) ? 0 : k));

  V0 = (sh < 64)  ? (Pc << (sh & 63)) : 0ull;
  V1 = (sh == 0)  ? 0ull :
       (sh < 64)  ? (Pc >> ((64 - sh) & 63)) :
       (sh < 128) ? (Pc << ((sh - 64) & 63)) : 0ull;
  V2 = (sh <= 64) ? 0ull :
       (sh < 128) ? (Pc >> ((128 - sh) & 63)) :
                    (Pc << ((sh - 128) & 63));
  V2 = (V2 & 0x0000FFFFFFFFFFFFull) | ((uint64_t)f2bf(sil) << 48);
}

__device__ __forceinline__ void async16(const u16* g, u16* l) {
  __builtin_amdgcn_global_load_lds(
      (const __attribute__((address_space(1))) uint32_t*)g,
      (__attribute__((address_space(3))) uint32_t*)l,
      16, 0, 0);
}

// ---------------- prep: pack Wt (blocks 0..4095) + expand X (blocks 4096..5119).
// Expand v2: 8 rows/block, DOUBLE-BUFFERED LDS funnel -> one sync per row;
// global stores of row r overlap the VALU expansion of row r+1 (old version's
// 2 syncs/row serialized expand->LDS->store, holding it at 2.7 TB/s).
__global__ __launch_bounds__(256) void prep_kernel(
    const float* __restrict__ coeff, const float* __restrict__ sb,
    const float* __restrict__ ss_p, u16* __restrict__ Wt,
    const float* __restrict__ X, const float* __restrict__ grid,
    u16* __restrict__ Aexp)
{
  __shared__ __align__(16) char smem_c[49152];
  const int tid = threadIdx.x;

  if (blockIdx.x < 4096) {
    // ---- pack Wt: bf16 [OUT_DIM][KDIM] (verified, unchanged)
    float* cf = (float*)smem_c;                 // 11264 B
    u16*   st = (u16*)(smem_c + 11264);         // 6144 B
    const int b   = blockIdx.x;
    const int o   = b >> 2;
    const int i0  = (b & 3) * 256;
    const float* cbase = coeff + (size_t)o * (IN_DIM * NG) + (size_t)i0 * NG;
#pragma unroll
    for (int p = 0; p < NG; ++p) cf[p * 256 + tid] = cbase[p * 256 + tid];
    const float ss  = ss_p[0];
    const float sbv = sb[(size_t)o * IN_DIM + i0 + tid];
    __syncthreads();
    const float* cp = cf + tid * NG;
    u16 h[GK];
#pragma unroll
    for (int g = 0; g < NG; ++g) h[g] = f2bf(cp[g] * ss);
    h[NG] = f2bf(sbv);
    uint64_t V0 = (uint64_t)h[0] | ((uint64_t)h[1] << 16) | ((uint64_t)h[2] << 32) | ((uint64_t)h[3] << 48);
    uint64_t V1 = (uint64_t)h[4] | ((uint64_t)h[5] << 16) | ((uint64_t)h[6] << 32) | ((uint64_t)h[7] << 48);
    uint64_t V2 = (uint64_t)h[8] | ((uint64_t)h[9] << 16) | ((uint64_t)h[10] << 32) | ((uint64_t)h[11] << 48);
    uint64_t* sp = (uint64_t*)(st + tid * GK);
    sp[0] = V0; sp[1] = V1; sp[2] = V2;
    __syncthreads();
    const uint4* src = (const uint4*)st;
    uint4* dst = (uint4*)(Wt + (size_t)b * (256 * GK));
    dst[tid] = src[tid];
    if (tid < 128) dst[256 + tid] = src[256 + tid];
  } else {
    // ---- expand X -> Aexp, 8 rows/block, double-buffered funnel
    uint4 (*st4)[1536] = (uint4 (*)[1536])smem_c;   // 2 x 24576 B
    const float g0    = grid[0];
    const float inv_h = 1.0f / (grid[1] - grid[0]);
    const int bb   = blockIdx.x - 4096;             // 0..1023
    const int row0 = bb * 8;

    uint64_t ev[12];
    // expand row 0 -> buf 0
    {
      float4 xv = *(const float4*)(X + (size_t)row0 * IN_DIM + tid * 4);
      expand_regs(xv.x, g0, inv_h, ev[0], ev[1], ev[2]);
      expand_regs(xv.y, g0, inv_h, ev[3], ev[4], ev[5]);
      expand_regs(xv.z, g0, inv_h, ev[6], ev[7], ev[8]);
      expand_regs(xv.w, g0, inv_h, ev[9], ev[10], ev[11]);
#pragma unroll
      for (int j = 0; j < 6; ++j) {
        uint4 w;
        w.x = (uint32_t)ev[2*j];     w.y = (uint32_t)(ev[2*j] >> 32);
        w.z = (uint32_t)ev[2*j+1];   w.w = (uint32_t)(ev[2*j+1] >> 32);
        st4[0][tid * 6 + j] = w;
      }
    }
    __syncthreads();

    for (int rr = 0; rr < 8; ++rr) {
      const int p = rr & 1;
      // read row rr from buf p (coalesced view)
      uint4 v[6];
#pragma unroll
      for (int j = 0; j < 6; ++j) v[j] = st4[p][j * 256 + tid];
      // expand row rr+1 (independent VALU; overlaps the stores below)
      if (rr + 1 < 8) {
        float4 xv = *(const float4*)(X + (size_t)(row0 + rr + 1) * IN_DIM + tid * 4);
        expand_regs(xv.x, g0, inv_h, ev[0], ev[1], ev[2]);
        expand_regs(xv.y, g0, inv_h, ev[3], ev[4], ev[5]);
        expand_regs(xv.z, g0, inv_h, ev[6], ev[7], ev[8]);
        expand_regs(xv.w, g0, inv_h, ev[9], ev[10], ev[11]);
      }
      // store row rr to global (coalesced 24KB)
      uint4* dst = (uint4*)(Aexp + (size_t)(row0 + rr) * KDIM);
#pragma unroll
      for (int j = 0; j < 6; ++j) dst[j * 256 + tid] = v[j];
      // write row rr+1 into buf p^1
      if (rr + 1 < 8) {
#pragma unroll
        for (int j = 0; j < 6; ++j) {
          uint4 w;
          w.x = (uint32_t)ev[2*j];     w.y = (uint32_t)(ev[2*j] >> 32);
          w.z = (uint32_t)ev[2*j+1];   w.w = (uint32_t)(ev[2*j+1] >> 32);
          st4[p ^ 1][tid * 6 + j] = w;
        }
      }
      __syncthreads();   // buf p^1 complete for next iter; buf p reads done
    }
  }
}

// ---------------- GEMM = round-4 verified core, byte-identical (best: 216us, 41%).
// 256x256 tile, BK=64, 8 waves, counted-vmcnt pipeline: combined DMA index
// q = wave + 8j (j<9) over 72 ops (36 A + 36 B) -> exactly 9 ops/wave;
// vmcnt(9) certifies tile t+1 while leaving t+2's batch in flight.
// Pad-granule LDS (9 granules/row, 144B stride) -> measured 0 conflicts.
// Epilogue: plain stores + part + reduce (r8: atomics cost +35us).
// SETTLED BY r3/r7/r9/r10: non-uniform vmcnt, phase-split, XCD-B pinning,
// and 3-deep BK=32 all regress vs this structure. Remaining lever = full
// m201 8-phase template (exact port only).
__global__ __launch_bounds__(512, 2) void gemm_pre_kernel(
    const u16* __restrict__ A, const u16* __restrict__ Wt,
    float* __restrict__ out, float* __restrict__ part, int k_iters)
{
  __shared__ __align__(16) u16 S[4 * ABUF];   // 147456 B

  const int tid  = threadIdx.x;
  const int lane = tid & 63;
  const int wave = tid >> 6;              // 0..7
  const int s    = blockIdx.x >> 7;       // 2 K-splits
  const int r    = blockIdx.x & 127;
  const int bm   = r & 31;                // bid%8 = bm%8 -> A-strip sharers on one XCD
  const int bn   = r >> 5;
  const int wm   = (wave >> 2) * 128;     // 2 M-warps
  const int wn   = (wave & 3) * 64;       // 4 N-warps
  const int l31  = lane & 31;
  const int g8   = lane >> 5;

  floatx16 acc[4][2];
#pragma unroll
  for (int a = 0; a < 4; ++a)
#pragma unroll
    for (int b = 0; b < 2; ++b)
#pragma unroll
      for (int rr = 0; rr < 16; ++rr) acc[a][b][rr] = 0.f;

  // DMA setup: combined op q = wave + 8j (j<9, q<72): q<36 -> A granule-op q,
  // else B granule-op q-36. lane: gidx = oq*64+lane; row = gidx/9;
  // chunk = gidx%9; chunk 8 = pad -> harmless dup of chunk 0.
  const size_t k0 = (size_t)s * k_iters * GBK;
  const u16* src[9]; int dof[9];
#pragma unroll
  for (int j = 0; j < 9; ++j) {
    int q    = wave + 8 * j;
    bool isA = (q < 36);
    int oq   = isA ? q : q - 36;
    int gidx  = oq * 64 + lane;
    int row   = gidx / 9;
    int chunk = gidx - row * 9;
    int c8    = (chunk == 8) ? 0 : chunk;
    src[j] = (isA ? A + (size_t)(bm * 256 + row) * KDIM
                  : Wt + (size_t)(bn * 256 + row) * KDIM) + k0 + c8 * 8;
    dof[j] = (isA ? 0 : 2 * ABUF) + oq * 512;   // 64 granules = 1024 B per op
  }

  const int NT = k_iters;

  // prologue: tile 0 -> parity 0 (drain), tile 1 -> parity 1 (left in flight)
#pragma unroll
  for (int j = 0; j < 9; ++j) async16(src[j], S + dof[j]);
  asm volatile("s_waitcnt vmcnt(0)" ::: "memory");
  __builtin_amdgcn_s_barrier();
  __builtin_amdgcn_sched_barrier(0);
#pragma unroll
  for (int j = 0; j < 9; ++j) async16(src[j] + GBK, S + ABUF + dof[j]);

  for (int t = 0; t < NT; ++t) {
    const u16* Ab = S + (t & 1) * ABUF;
    const u16* Bb = S + 2 * ABUF + (t & 1) * ABUF;

    __builtin_amdgcn_s_setprio(1);
#pragma unroll
    for (int ks = 0; ks < 4; ++ks) {
      short8 bf0 = *(const short8*)&Bb[(wn +      l31) * 72 + (2 * ks + g8) * 8];
      short8 bf1 = *(const short8*)&Bb[(wn + 32 + l31) * 72 + (2 * ks + g8) * 8];
#pragma unroll
      for (int m = 0; m < 4; ++m) {
        short8 af = *(const short8*)&Ab[(wm + m * 32 + l31) * 72 + (2 * ks + g8) * 8];
        acc[m][0] = __builtin_amdgcn_mfma_f32_32x32x16_bf16(af, bf0, acc[m][0], 0, 0, 0);
        acc[m][1] = __builtin_amdgcn_mfma_f32_32x32x16_bf16(af, bf1, acc[m][1], 0, 0, 0);
      }
    }
    __builtin_amdgcn_s_setprio(0);

    __builtin_amdgcn_s_barrier();          // all waves done reading parity (t&1)
    __builtin_amdgcn_sched_barrier(0);
    if (t + 2 < NT) {
      u16* D = S + (t & 1) * ABUF;         // just-freed parity
      const size_t ko = (size_t)(t + 2) * GBK;
#pragma unroll
      for (int j = 0; j < 9; ++j) async16(src[j] + ko, D + dof[j]);
      asm volatile("s_waitcnt vmcnt(9)" ::: "memory");   // t+1 certified; t+2 in flight
    } else {
      asm volatile("s_waitcnt vmcnt(0)" ::: "memory");
    }
    __builtin_amdgcn_s_barrier();          // parity (t+1)&1 ready for next iter
    __builtin_amdgcn_sched_barrier(0);
  }

  // C/D map (m74/m101-verified): col=lane&31, row=(reg&3)+8*(reg>>2)+4*(lane>>5)
  float* op = (s == 0) ? out : part;
#pragma unroll
  for (int m = 0; m < 4; ++m)
#pragma unroll
    for (int n = 0; n < 2; ++n) {
      const int row0 = bm * 256 + wm + m * 32 + 4 * g8;
      const int col  = bn * 256 + wn + n * 32 + l31;
#pragma unroll
      for (int reg = 0; reg < 16; ++reg) {
        int row = row0 + (reg & 3) + 8 * (reg >> 2);
        op[(size_t)row * OUT_DIM + col] = acc[m][n][reg];
      }
    }
}

// out += part, float4-vectorized
__global__ __launch_bounds__(256) void reduce_kernel(
    float* __restrict__ out, const float* __restrict__ part)
{
  size_t i = (size_t)blockIdx.x * 256 + threadIdx.x;
  float4* o = (float4*)out;
  const float4* p = (const float4*)part;
  float4 a = o[i], b = p[i];
  a.x += b.x; a.y += b.y; a.z += b.z; a.w += b.w;
  o[i] = a;
}

// ---------------- fallback path (round-5 fused kernel, verified pass) ----------------
__device__ __forceinline__ void expand2(float2 xv, float g0, float inv_h, uint64_t e[6]) {
  expand_regs(xv.x, g0, inv_h, e[0], e[1], e[2]);
  expand_regs(xv.y, g0, inv_h, e[3], e[4], e[5]);
}
__device__ __forceinline__ void write_ev(u16* abase, int awoff, const uint64_t e[6]) {
  uint4* w = (uint4*)(abase + awoff);
  uint4 w0, w1, w2;
  w0.x = (uint32_t)e[0]; w0.y = (uint32_t)(e[0] >> 32);
  w0.z = (uint32_t)e[1]; w0.w = (uint32_t)(e[1] >> 32);
  w1.x = (uint32_t)e[2]; w1.y = (uint32_t)(e[2] >> 32);
  w1.z = (uint32_t)e[3]; w1.w = (uint32_t)(e[3] >> 32);
  w2.x = (uint32_t)e[4]; w2.y = (uint32_t)(e[4] >> 32);
  w2.z = (uint32_t)e[5]; w2.w = (uint32_t)(e[5] >> 32);
  w[0] = w0; w[1] = w1; w[2] = w2;
}

__global__ __launch_bounds__(256) void pack_wt_kernel(
    const float* __restrict__ coeff, const float* __restrict__ sb,
    const float* __restrict__ ss_p, u16* __restrict__ Wt)
{
  __shared__ float cf[256 * NG];
  __shared__ __align__(16) u16 st[256 * GK];
  const int tid = threadIdx.x;
  const int b   = blockIdx.x;
  const int o   = b >> 2;
  const int i0  = (b & 3) * 256;
  const float* cbase = coeff + (size_t)o * (IN_DIM * NG) + (size_t)i0 * NG;
#pragma unroll
  for (int p = 0; p < NG; ++p) cf[p * 256 + tid] = cbase[p * 256 + tid];
  const float ss  = ss_p[0];
  const float sbv = sb[(size_t)o * IN_DIM + i0 + tid];
  __syncthreads();
  const float* cp = cf + tid * NG;
  u16 h[GK];
#pragma unroll
  for (int g = 0; g < NG; ++g) h[g] = f2bf(cp[g] * ss);
  h[NG] = f2bf(sbv);
  uint64_t V0 = (uint64_t)h[0] | ((uint64_t)h[1] << 16) | ((uint64_t)h[2] << 32) | ((uint64_t)h[3] << 48);
  uint64_t V1 = (uint64_t)h[4] | ((uint64_t)h[5] << 16) | ((uint64_t)h[6] << 32) | ((uint64_t)h[7] << 48);
  uint64_t V2 = (uint64_t)h[8] | ((uint64_t)h[9] << 16) | ((uint64_t)h[10] << 32) | ((uint64_t)h[11] << 48);
  uint64_t* sp = (uint64_t*)(st + tid * GK);
  sp[0] = V0; sp[1] = V1; sp[2] = V2;
  __syncthreads();
  const uint4* src = (const uint4*)st;
  uint4* dst = (uint4*)(Wt + (size_t)b * (256 * GK));
  dst[tid] = src[tid];
  if (tid < 128) dst[256 + tid] = src[256 + tid];
}

__global__ __launch_bounds__(512, 2) void gemm_fused2_kernel(
    const float* __restrict__ X, const float* __restrict__ grid,
    const u16* __restrict__ Wt, float* __restrict__ out, float* __restrict__ part,
    int k_iters)
{
  __shared__ __align__(16) u16 S[4 * FBUF];

  const int tid  = threadIdx.x;
  const int lane = tid & 63;
  const int wave = tid >> 6;
  const int s    = blockIdx.x >> 7;
  const int r    = blockIdx.x & 127;
  const int bm   = r & 31;
  const int bn   = r >> 5;
  const int wm   = (wave >> 2) * 128;
  const int wn   = (wave & 3) * 64;
  const int l31  = lane & 31;
  const int g8   = lane >> 5;

  const float g0    = grid[0];
  const float inv_h = 1.0f / (grid[1] - grid[0]);

  floatx16 acc[4][2];
#pragma unroll
  for (int a = 0; a < 4; ++a)
#pragma unroll
    for (int b = 0; b < 2; ++b)
#pragma unroll
      for (int rr = 0; rr < 16; ++rr) acc[a][b][rr] = 0.f;

  const int kb = s * k_iters * FBK;
  const u16* bsrc[FOPS]; int bdof[FOPS];
#pragma unroll
  for (int j = 0; j < FOPS; ++j) {
    int o  = wave + 8 * j;
    int oc = (o < 28) ? o : 27;
    int gidx = oc * 64 + lane;
    int row  = gidx / 7;
    int sl   = gidx - row * 7;
    int c6   = (sl == 6) ? 0 : sl;
    bsrc[j] = Wt + (size_t)(bn * 256 + row) * KDIM + kb + c6 * 8;
    bdof[j] = oc * 512;
  }

  const int arow  = tid >> 1;
  const int cp    = (tid & 1) * 2;
  const float* xp = X + (size_t)(bm * 256 + arow) * IN_DIM + s * (k_iters * 4) + cp;
  const int awoff = arow * FROW + cp * 12;

  const int NT = k_iters;

  float2 x0    = *(const float2*)(xp + 0);
  float2 x1    = *(const float2*)(xp + 4);
  float2 x_use = *(const float2*)(xp + 8);
  float2 x_mid = *(const float2*)(xp + 12);
  float2 x_new = x_use;

#pragma unroll
  for (int j = 0; j < FOPS; ++j) async16(bsrc[j],       S + 2 * FBUF + bdof[j]);
#pragma unroll
  for (int j = 0; j < FOPS; ++j) async16(bsrc[j] + FBK, S + 3 * FBUF + bdof[j]);
  {
    uint64_t e[6];
    expand2(x0, g0, inv_h, e); write_ev(S, awoff, e);
    expand2(x1, g0, inv_h, e); write_ev(S + FBUF, awoff, e);
  }
  asm volatile("s_waitcnt vmcnt(0) lgkmcnt(0)" ::: "memory");
  __builtin_amdgcn_s_barrier();
  __builtin_amdgcn_sched_barrier(0);

  for (int t = 0; t < NT; ++t) {
    const int p = t & 1;
    const u16* Ab = S + p * FBUF;
    const u16* Bb = S + 2 * FBUF + p * FBUF;

    uint64_t e[6];
    const bool dostage = (t + 2 < NT);
    if (dostage) expand2(x_use, g0, inv_h, e);

    __builtin_amdgcn_s_setprio(1);
#pragma unroll
    for (int ks = 0; ks < 3; ++ks) {
      const int cc = (2 * ks + g8) * 8;
      short8 bf0 = *(const short8*)&Bb[(wn +      l31) * FROW + cc];
      short8 bf1 = *(const short8*)&Bb[(wn + 32 + l31) * FROW + cc];
#pragma unroll
      for (int m = 0; m < 4; ++m) {
        short8 af = *(const short8*)&Ab[(wm + m * 32 + l31) * FROW + cc];
        acc[m][0] = __builtin_amdgcn_mfma_f32_32x32x16_bf16(af, bf0, acc[m][0], 0, 0, 0);
        acc[m][1] = __builtin_amdgcn_mfma_f32_32x32x16_bf16(af, bf1, acc[m][1], 0, 0, 0);
      }
    }
    __builtin_amdgcn_s_setprio(0);

    __builtin_amdgcn_s_barrier();
    __builtin_amdgcn_sched_barrier(0);

    if (dostage) {
      const int ko = (t + 2) * FBK;
      u16* Bd = S + 2 * FBUF + p * FBUF;
#pragma unroll
      for (int j = 0; j < FOPS; ++j) async16(bsrc[j] + ko, Bd + bdof[j]);
      write_ev(S + p * FBUF, awoff, e);
      if (t + 4 < NT) {
        x_new = *(const float2*)(xp + (size_t)(t + 4) * 4);
        asm volatile("s_waitcnt vmcnt(5) lgkmcnt(0)" ::: "memory");
      } else {
        asm volatile("s_waitcnt vmcnt(4) lgkmcnt(0)" ::: "memory");
      }
    } else {
      asm volatile("s_waitcnt vmcnt(0) lgkmcnt(0)" ::: "memory");
    }
    __builtin_amdgcn_s_barrier();
    __builtin_amdgcn_sched_barrier(0);

    x_use = x_mid; x_mid = x_new;
  }

  float* op = (s == 0) ? out : part;
#pragma unroll
  for (int m = 0; m < 4; ++m)
#pragma unroll
    for (int n = 0; n < 2; ++n) {
      const int row0 = bm * 256 + wm + m * 32 + 4 * g8;
      const int col  = bn * 256 + wn + n * 32 + l31;
#pragma unroll
      for (int reg = 0; reg < 16; ++reg) {
        int row = row0 + (reg & 3) + 8 * (reg >> 2);
        op[(size_t)row * OUT_DIM + col] = acc[m][n][reg];
      }
    }
}

extern "C" void kernel_launch(void* const* d_in, const int* in_sizes, int n_in,
                              void* d_out, int out_size, void* d_ws, size_t ws_size,
                              hipStream_t stream) {
  const float* x     = (const float*)d_in[0];
  const float* grid  = (const float*)d_in[1];
  const float* coeff = (const float*)d_in[2];
  const float* sb    = (const float*)d_in[3];
  const float* ss    = (const float*)d_in[4];
  float* out = (float*)d_out;

  u16* Wt = (u16*)d_ws;
  const size_t wt_bytes   = (size_t)OUT_DIM * KDIM * 2;     // 25.2 MB
  const size_t aexp_bytes = (size_t)TOKENS * KDIM * 2;      // 201.3 MB
  const size_t part_bytes = (size_t)TOKENS * OUT_DIM * 4;   // 33.6 MB

  if (ws_size >= wt_bytes + aexp_bytes + part_bytes) {
    // main path: fused prep (pipelined expand), r4-exact GEMM, reduce.
    u16*   Aexp = (u16*)((char*)d_ws + wt_bytes);
    float* part = (float*)((char*)d_ws + wt_bytes + aexp_bytes);
    prep_kernel<<<4096 + TOKENS / 8, 256, 0, stream>>>(coeff, sb, ss, Wt, x, grid, Aexp);
    gemm_pre_kernel<<<128 * 2, 512, 0, stream>>>(Aexp, Wt, out, part, 96);
    reduce_kernel<<<(TOKENS * OUT_DIM / 4) / 256, 256, 0, stream>>>(out, part);
  } else if (ws_size >= wt_bytes + part_bytes) {
    // fallback: fused split-K=2 (round-5 kernel, verified)
    float* part = (float*)((char*)d_ws + wt_bytes);
    pack_wt_kernel<<<(OUT_DIM * IN_DIM) / 256, 256, 0, stream>>>(coeff, sb, ss, Wt);
    gemm_fused2_kernel<<<128 * 2, 512, 0, stream>>>(x, grid, Wt, out, part, 128);
    reduce_kernel<<<(TOKENS * OUT_DIM / 4) / 256, 256, 0, stream>>>(out, part);
  } else {
    pack_wt_kernel<<<(OUT_DIM * IN_DIM) / 256, 256, 0, stream>>>(coeff, sb, ss, Wt);
    gemm_fused2_kernel<<<128, 512, 0, stream>>>(x, grid, Wt, out, nullptr, 256);
  }
}